// Round 1
// baseline (15198.787 us; speedup 1.0000x reference)
//
#include <hip/hip_runtime.h>
#include <hip/hip_bf16.h>

#define NB    64      // batch rows
#define NSTEP 512     // T*H*W sequence length
#define EDIM  512     // input feature dim
#define REC   2048    // recurrent dim
#define KSEL  819     // int(2048*0.4)
#define NKC   16      // K-split partial chunks

static __device__ inline unsigned short f2bf(float f) {
    __hip_bfloat16 h = __float2bfloat16(f);
    unsigned short u;
    __builtin_memcpy(&u, &h, 2);
    return u;
}

// ---------------------------------------------------------------------------
// Partial GEMM: outp[kc][m][n] = sum_{k in chunk kc} A[m][k]*B[k][n]
// M=64 fixed, N=2048 (16 col-blocks of 128), K split across gridDim.y chunks.
// A row m at A + m*a_row_stride + a_col_off (lets the same kernel serve both
// r@W_recurrent and x_t@W_input).
// ---------------------------------------------------------------------------
template<int KCHUNK, int BK>
__global__ __launch_bounds__(256)
void gemm_part_kernel(const float* __restrict__ A, int a_row_stride, int a_col_off,
                      const float* __restrict__ B, float* __restrict__ outp)
{
    const int cc = blockIdx.x;          // col chunk (128 cols)
    const int kc = blockIdx.y;          // K chunk
    const int n0 = cc * 128;
    const int k0 = kc * KCHUNK;
    __shared__ float aS[BK][64];        // A transposed: aS[k][m]
    __shared__ float bS[BK][128];       // B row-major tile
    const int tid = threadIdx.x;
    const int tx = tid & 31;            // col group: 4 cols
    const int ty = tid >> 5;            // row group: 8 rows
    float4 acc[8];
#pragma unroll
    for (int i = 0; i < 8; ++i) acc[i] = make_float4(0.f, 0.f, 0.f, 0.f);

    for (int kb = 0; kb < KCHUNK; kb += BK) {
        {   // stage A: 64 x BK, transposed
            const int lm = tid & 63;
            const int kbase = (tid >> 6) * (BK / 4);
            const float* arow = A + (long long)lm * a_row_stride + (a_col_off + k0 + kb + kbase);
#pragma unroll
            for (int i = 0; i < BK / 4; i += 4) {
                float4 v = *(const float4*)(arow + i);
                aS[kbase + i    ][lm] = v.x;
                aS[kbase + i + 1][lm] = v.y;
                aS[kbase + i + 2][lm] = v.z;
                aS[kbase + i + 3][lm] = v.w;
            }
        }
        {   // stage B: BK x 128
            const int nn = tx * 4;
#pragma unroll
            for (int kk = ty; kk < BK; kk += 8) {
                float4 v = *(const float4*)(B + (long long)(k0 + kb + kk) * REC + n0 + nn);
                *(float4*)&bS[kk][nn] = v;
            }
        }
        __syncthreads();
#pragma unroll 8
        for (int kk = 0; kk < BK; ++kk) {
            float4 bv = *(const float4*)&bS[kk][tx * 4];
            float4 a0 = *(const float4*)&aS[kk][ty * 8];
            float4 a1 = *(const float4*)&aS[kk][ty * 8 + 4];
            float av[8] = {a0.x, a0.y, a0.z, a0.w, a1.x, a1.y, a1.z, a1.w};
#pragma unroll
            for (int i = 0; i < 8; ++i) {
                acc[i].x += av[i] * bv.x;
                acc[i].y += av[i] * bv.y;
                acc[i].z += av[i] * bv.z;
                acc[i].w += av[i] * bv.w;
            }
        }
        __syncthreads();
    }
    float* op = outp + (long long)kc * (NB * REC);
#pragma unroll
    for (int i = 0; i < 8; ++i) {
        *(float4*)&op[(ty * 8 + i) * REC + n0 + tx * 4] = acc[i];
    }
}

// ---------------------------------------------------------------------------
// Precompute Y[t*64+b][j] = sum_e x[b][t][e] * W_in[e][j], stored bf16.
// Grid: (16 col-chunks, 512 t-blocks). M-block = 64 rows (= one t, all b).
// ---------------------------------------------------------------------------
__global__ __launch_bounds__(256)
void y_precompute(const float* __restrict__ x, const float* __restrict__ Wi,
                  unsigned short* __restrict__ Y)
{
    const int cc = blockIdx.x;          // 0..15
    const int rb = blockIdx.y;          // 0..511 (= t)
    const int n0 = cc * 128;
    __shared__ float aS[32][64];
    __shared__ float bS[32][128];
    const int tid = threadIdx.x;
    const int tx = tid & 31;
    const int ty = tid >> 5;
    float4 acc[8];
#pragma unroll
    for (int i = 0; i < 8; ++i) acc[i] = make_float4(0.f, 0.f, 0.f, 0.f);

    for (int k0 = 0; k0 < EDIM; k0 += 32) {
        {
            const int lm = tid & 63;               // = b
            const int kbase = (tid >> 6) * 8;
            const float* arow = x + (long long)lm * (NSTEP * EDIM) + rb * EDIM + k0 + kbase;
#pragma unroll
            for (int i = 0; i < 8; i += 4) {
                float4 v = *(const float4*)(arow + i);
                aS[kbase + i    ][lm] = v.x;
                aS[kbase + i + 1][lm] = v.y;
                aS[kbase + i + 2][lm] = v.z;
                aS[kbase + i + 3][lm] = v.w;
            }
        }
        {
            const int nn = tx * 4;
#pragma unroll
            for (int kk = ty; kk < 32; kk += 8) {
                float4 v = *(const float4*)(Wi + (long long)(k0 + kk) * REC + n0 + nn);
                *(float4*)&bS[kk][nn] = v;
            }
        }
        __syncthreads();
#pragma unroll 8
        for (int kk = 0; kk < 32; ++kk) {
            float4 bv = *(const float4*)&bS[kk][tx * 4];
            float4 a0 = *(const float4*)&aS[kk][ty * 8];
            float4 a1 = *(const float4*)&aS[kk][ty * 8 + 4];
            float av[8] = {a0.x, a0.y, a0.z, a0.w, a1.x, a1.y, a1.z, a1.w};
#pragma unroll
            for (int i = 0; i < 8; ++i) {
                acc[i].x += av[i] * bv.x;
                acc[i].y += av[i] * bv.y;
                acc[i].z += av[i] * bv.z;
                acc[i].w += av[i] * bv.w;
            }
        }
        __syncthreads();
    }
#pragma unroll
    for (int i = 0; i < 8; ++i) {
        const long long m = (long long)rb * 64 + ty * 8 + i;
        ushort4 o;
        o.x = f2bf(acc[i].x);
        o.y = f2bf(acc[i].y);
        o.z = f2bf(acc[i].z);
        o.w = f2bf(acc[i].w);
        *(ushort4*)&Y[m * REC + n0 + tx * 4] = o;
    }
}

// ---------------------------------------------------------------------------
// Per-step update: sum z partials, exact top-KSEL threshold via MSD radix
// select (index-ordered tie-break), r = normalize(tanh(y + masked z)).
// One block per batch row b. 256 threads, 8 elements each.
// ---------------------------------------------------------------------------
__global__ __launch_bounds__(256)
void update_kernel(const float* __restrict__ zpart,
                   const unsigned short* __restrict__ Ybf,
                   const float* __restrict__ ypart,
                   int use_bf16_y, int t,
                   float* __restrict__ r)
{
    const int b = blockIdx.x;
    const int tid = threadIdx.x;
    __shared__ unsigned int kS[REC];
    __shared__ unsigned char selS[REC];
    __shared__ unsigned int hist[256];
    __shared__ unsigned int s_byte, s_newrem;
    __shared__ float red[4];
    __shared__ float s_norm;

    // 1) z row = sum of K-split partials; monotone key transform
    float zr[8];
#pragma unroll
    for (int s = 0; s < 8; ++s) {
        const int j = tid + 256 * s;
        float a = 0.f;
#pragma unroll
        for (int kc = 0; kc < NKC; ++kc)
            a += zpart[(long long)kc * (NB * REC) + b * REC + j];
        zr[s] = a;
        const unsigned int u = __float_as_uint(a);
        kS[j] = (u & 0x80000000u) ? ~u : (u | 0x80000000u);   // desc unsigned == desc value
    }
    __syncthreads();

    // 2) MSD radix select: find key T of the KSEL-th largest
    unsigned int prefix = 0, remaining = KSEL;
    for (int byte = 3; byte >= 0; --byte) {
        hist[tid] = 0u;
        __syncthreads();
        const int shift = byte * 8;
        const unsigned int pmask = (byte == 3) ? 0u : (0xFFFFFFFFu << (shift + 8));
#pragma unroll
        for (int s = 0; s < 8; ++s) {
            const unsigned int key = kS[tid + 256 * s];
            if ((key & pmask) == prefix)
                atomicAdd(&hist[(key >> shift) & 255u], 1u);
        }
        __syncthreads();
        if (tid < 64) {   // wave 0: suffix-sum over 256 bins, 4 bins/lane
            const unsigned int h0 = hist[tid * 4 + 0];
            const unsigned int h1 = hist[tid * 4 + 1];
            const unsigned int h2 = hist[tid * 4 + 2];
            const unsigned int h3 = hist[tid * 4 + 3];
            const unsigned int tot = h0 + h1 + h2 + h3;
            unsigned int suf = tot;   // will become sum of bins [4*tid .. 255]
#pragma unroll
            for (int st = 1; st < 64; st <<= 1) {
                unsigned int o = __shfl_down(suf, (unsigned)st);
                if (tid + st >= 64) o = 0u;
                suf += o;
            }
            unsigned int S[5];
            S[0] = suf;                 // suffix at bin 4*tid
            S[1] = suf - h0;
            S[2] = suf - h0 - h1;
            S[3] = suf - h0 - h1 - h2;
            S[4] = suf - tot;           // suffix at next lane's first bin
#pragma unroll
            for (int q = 0; q < 4; ++q) {
                if (S[q] >= remaining && S[q + 1] < remaining) {
                    s_byte = (unsigned int)(tid * 4 + q);
                    s_newrem = remaining - S[q + 1];
                }
            }
        }
        __syncthreads();
        prefix |= (s_byte << shift);
        remaining = s_newrem;
        __syncthreads();
    }
    const unsigned int T = prefix;
    const unsigned int need = remaining;             // # of ==T entries to keep
    const unsigned int cnteq = hist[T & 255u];       // total # of ==T entries

    // 3) selection mask (index-ordered tie-break matches lax.top_k)
    if (need == cnteq) {
#pragma unroll
        for (int s = 0; s < 8; ++s) {
            const int j = tid + 256 * s;
            selS[j] = (kS[j] >= T) ? 1 : 0;
        }
    } else if (tid == 0) {             // rare tie path (hit at step 0: all zeros)
        unsigned int rem = need;
        for (int j = 0; j < REC; ++j) {
            const unsigned int k = kS[j];
            unsigned char sel = 0;
            if (k > T) sel = 1;
            else if (k == T && rem > 0u) { sel = 1; --rem; }
            selS[j] = sel;
        }
    }
    __syncthreads();

    // 4) r_new = tanh(y + masked z); row-normalize
    float rn[8];
    float sumsq = 0.f;
    const long long yrow = ((long long)t * NB + b) * REC;
#pragma unroll
    for (int s = 0; s < 8; ++s) {
        const int j = tid + 256 * s;
        float y;
        if (use_bf16_y) {
            const unsigned int w = ((unsigned int)Ybf[yrow + j]) << 16;
            y = __uint_as_float(w);
        } else {
            float a = 0.f;
#pragma unroll
            for (int kc = 0; kc < NKC; ++kc)
                a += ypart[(long long)kc * (NB * REC) + b * REC + j];
            y = a;
        }
        const float v = y + (selS[j] ? zr[s] : 0.f);
        const float th = tanhf(v);
        rn[s] = th;
        sumsq += th * th;
    }
#pragma unroll
    for (int off = 32; off > 0; off >>= 1) sumsq += __shfl_down(sumsq, (unsigned)off);
    const int lane = tid & 63, wid = tid >> 6;
    if (lane == 0) red[wid] = sumsq;
    __syncthreads();
    if (tid == 0) s_norm = sqrtf(red[0] + red[1] + red[2] + red[3]) + 1e-6f;
    __syncthreads();
    const float inv = 1.0f / s_norm;
#pragma unroll
    for (int s = 0; s < 8; ++s)
        r[(long long)b * REC + tid + 256 * s] = rn[s] * inv;
}

// ---------------------------------------------------------------------------
extern "C" void kernel_launch(void* const* d_in, const int* in_sizes, int n_in,
                              void* d_out, int out_size, void* d_ws, size_t ws_size,
                              hipStream_t stream)
{
    const float* x   = (const float*)d_in[0];   // [64][512][512]
    const float* Win = (const float*)d_in[1];   // [512][2048]
    const float* Wr  = (const float*)d_in[2];   // [2048][2048]
    float* r = (float*)d_out;                   // [64][2048] — recurrent state lives here

    char* ws = (char*)d_ws;
    const size_t ZPB = (size_t)NKC * NB * REC * sizeof(float);          // 8 MB z partials
    const size_t YB  = (size_t)NSTEP * NB * REC * sizeof(unsigned short); // 134 MB bf16 Y
    float* zpart = (float*)ws;
    unsigned short* Y = (unsigned short*)(ws + ZPB);   // Tier B
    float* ypart      = (float*)(ws + ZPB);            // Tier C (same region)
    const int tierB = (ws_size >= ZPB + YB) ? 1 : 0;

    // r0 = 0
    hipMemsetAsync(d_out, 0, (size_t)NB * REC * sizeof(float), stream);

    if (tierB) {
        y_precompute<<<dim3(16, NSTEP), 256, 0, stream>>>(x, Win, Y);
    }

    for (int t = 0; t < NSTEP; ++t) {
        if (!tierB) {
            // y partials for this step: K=512 split into 16 chunks of 32
            gemm_part_kernel<32, 32><<<dim3(16, NKC), 256, 0, stream>>>(
                x, NSTEP * EDIM, t * EDIM, Win, ypart);
        }
        // z partials: K=2048 split into 16 chunks of 128
        gemm_part_kernel<128, 64><<<dim3(16, NKC), 256, 0, stream>>>(
            r, REC, 0, Wr, zpart);
        update_kernel<<<NB, 256, 0, stream>>>(zpart, Y, ypart, tierB, t, r);
    }
}